// Round 22
// baseline (458.700 us; speedup 1.0000x reference)
//
#include <hip/hip_runtime.h>
#include <math.h>

#define EPSF 1e-7f
#define MAXNRM 10.0f
#define NB 391          // ceil(100000/256) buckets
#define RPB 256         // rows per bucket
#define EPT 16          // edges per thread in stage-1 scatter

using bf16x8 = __attribute__((ext_vector_type(8))) short;
using f32x4  = __attribute__((ext_vector_type(4))) float;
typedef unsigned short u16;

__device__ __forceinline__ float wsum(float v) {
    #pragma unroll
    for (int off = 32; off > 0; off >>= 1) v += __shfl_xor(v, off, 64);
    return v;
}

__device__ __forceinline__ u16 f2bf(float x) {   // RNE
    unsigned u = __float_as_uint(x);
    unsigned r = (u + 0x7FFFu + ((u >> 16) & 1u)) >> 16;
    return (u16)r;
}
__device__ __forceinline__ float bflo(unsigned u) { return __uint_as_float(u << 16); }
__device__ __forceinline__ float bfhi(unsigned u) { return __uint_as_float(u & 0xFFFF0000u); }

// ================= bodies =================

__device__ __forceinline__ void body_logmap(int bid, const float* __restrict__ eu,
                                            const float* __restrict__ ei, int Nu, int Ntot,
                                            float* __restrict__ out) {
    const int lane = threadIdx.x & 63;
    const int g = lane >> 4, q = lane & 15;
    const int n = bid * 16 + (threadIdx.x >> 6) * 4 + g;
    if (n >= Ntot) return;
    const float* src = (n < Nu) ? (eu + (size_t)n * 64) : (ei + (size_t)(n - Nu) * 64);
    const float x0 = src[0];
    const float alpha = fmaxf(x0, 1.0f + EPSF);
    const float coef = acoshf(alpha) / sqrtf(fmaxf(alpha * alpha - 1.0f, EPSF));
    const float4 v = *(const float4*)(src + q * 4);
    float4 o;
    o.x = (q == 0) ? 0.0f : coef * v.x;
    o.y = coef * v.y; o.z = coef * v.z; o.w = coef * v.w;
    *(float4*)(out + ((size_t)n << 6) + q * 4) = o;
}

__device__ __forceinline__ void body_bhist(int bid, int nblk, const int* __restrict__ rows,
                                           int nnz, int* __restrict__ bhist, int* h) {
    for (int j = threadIdx.x; j < NB; j += 256) h[j] = 0;
    __syncthreads();
    for (int i = bid * 256 + threadIdx.x; i < nnz; i += nblk * 256)
        atomicAdd(&h[rows[i] >> 8], 1);
    __syncthreads();
    for (int j = threadIdx.x; j < NB; j += 256)
        if (h[j]) atomicAdd(&bhist[j], h[j]);
}

__device__ __forceinline__ void body_moe(int bid, char* smem,
    const float* __restrict__ X, float* __restrict__ Y,
    const u16* __restrict__ Wt, const u16* __restrict__ Bt,
    const float* __restrict__ GW, const float* __restrict__ GB,
    u16* __restrict__ Bhout, int Ntot)
{
    float (*sX)[68] = (float(*)[68])smem;
    float (*sG)[8]  = (float(*)[8])(smem + 17408);
    float* sGW      = (float*)(smem + 17408 + 2048);
    const int tid = threadIdx.x;
    const int n0 = bid * 64;

    for (int i = tid; i < 64 * 16; i += 256) {
        const int rr = i >> 4, cc = i & 15;
        float4 v = make_float4(0.f, 0.f, 0.f, 0.f);
        if (n0 + rr < Ntot) v = *(const float4*)(X + (size_t)(n0 + rr) * 64 + cc * 4);
        *(float4*)&sX[rr][cc * 4] = v;
    }
    for (int i = tid; i < 512; i += 256) sGW[i] = GW[i];
    __syncthreads();

    {
        const int n = tid >> 2, e0 = (tid & 3) * 2;
        float lg0 = GB[e0], lg1 = GB[e0 + 1];
        #pragma unroll 8
        for (int d = 0; d < 64; ++d) {
            const float xv = sX[n][d];
            lg0 += xv * sGW[d * 8 + e0];
            lg1 += xv * sGW[d * 8 + e0 + 1];
        }
        sG[n][e0] = lg0; sG[n][e0 + 1] = lg1;
    }
    __syncthreads();
    if (tid < 64) {
        float ex[8], mx = -1e30f, s = 0.f;
        #pragma unroll
        for (int e = 0; e < 8; ++e) mx = fmaxf(mx, sG[tid][e]);
        #pragma unroll
        for (int e = 0; e < 8; ++e) { ex[e] = expf(sG[tid][e] - mx); s += ex[e]; }
        const float inv = 1.0f / s;
        #pragma unroll
        for (int e = 0; e < 8; ++e) sG[tid][e] = ex[e] * inv;
    }
    __syncthreads();

    const int w = tid >> 6, l = tid & 63;
    const int m = l & 15, kq = l >> 4;
    const int col = w * 16 + m;

    f32x4 zero = {0.f, 0.f, 0.f, 0.f};
    f32x4 acc[4];
    #pragma unroll
    for (int rt = 0; rt < 4; ++rt) acc[rt] = zero;

    bf16x8 bcur = *(const bf16x8*)(Wt + (((size_t)col) << 6) + kq * 8);

    #pragma unroll
    for (int kk = 0; kk < 16; ++kk) {
        const int e = kk >> 1;
        const int d0 = (kk & 1) * 32 + kq * 8;
        bf16x8 bnext = bcur;
        if (kk < 15) {
            const int e2 = (kk + 1) >> 1;
            const int d02 = ((kk + 1) & 1) * 32 + kq * 8;
            bnext = *(const bf16x8*)(Wt + (((size_t)(e2 * 64 + col)) << 6) + d02);
        }
        #pragma unroll
        for (int rt = 0; rt < 4; ++rt) {
            const int row = rt * 16 + m;
            const float gme = sG[row][e];
            const float4 xa = *(const float4*)&sX[row][d0];
            const float4 xb = *(const float4*)&sX[row][d0 + 4];
            union { bf16x8 v; u16 u[8]; } af;
            af.u[0] = f2bf(gme * xa.x); af.u[1] = f2bf(gme * xa.y);
            af.u[2] = f2bf(gme * xa.z); af.u[3] = f2bf(gme * xa.w);
            af.u[4] = f2bf(gme * xb.x); af.u[5] = f2bf(gme * xb.y);
            af.u[6] = f2bf(gme * xb.z); af.u[7] = f2bf(gme * xb.w);
            acc[rt] = __builtin_amdgcn_mfma_f32_16x16x32_bf16(af.v, bcur, acc[rt], 0, 0, 0);
        }
        bcur = bnext;
    }
    {
        bf16x8 z8 = {0, 0, 0, 0, 0, 0, 0, 0};
        bf16x8 bb = z8;
        if (kq == 0) bb = *(const bf16x8*)(Bt + (col << 3));
        #pragma unroll
        for (int rt = 0; rt < 4; ++rt) {
            union { bf16x8 v; u16 u[8]; } af;
            #pragma unroll
            for (int j = 0; j < 8; ++j)
                af.u[j] = (kq == 0) ? f2bf(sG[rt * 16 + m][j]) : (u16)0;
            acc[rt] = __builtin_amdgcn_mfma_f32_16x16x32_bf16(af.v, bb, acc[rt], 0, 0, 0);
        }
    }

    #pragma unroll
    for (int rt = 0; rt < 4; ++rt) {
        #pragma unroll
        for (int r = 0; r < 4; ++r) {
            const int row = rt * 16 + kq * 4 + r;
            if (n0 + row < Ntot) {
                Y[(size_t)(n0 + row) * 64 + col] = acc[rt][r];
                if (Bhout)
                    Bhout[(((size_t)(n0 + row)) << 6) + col] = f2bf(acc[rt][r]);
            }
        }
    }
}

__device__ __forceinline__ void body_bscatter(int bid, char* smem,
    const int* __restrict__ rows, const int* __restrict__ cols,
    const float* __restrict__ vals, int nnz,
    int* __restrict__ gcur, int2* __restrict__ tmp)
{
    int* lh = (int*)smem;
    int* lb = lh + NB;
    const int tid = threadIdx.x;
    for (int j = tid; j < NB; j += 256) lh[j] = 0;
    __syncthreads();

    const int base = bid * (256 * EPT);
    int r[EPT], c[EPT], lp[EPT];
    float v[EPT];
    #pragma unroll
    for (int j = 0; j < EPT; ++j) {
        const int i = base + j * 256 + tid;
        if (i < nnz) {
            r[j] = rows[i]; c[j] = cols[i]; v[j] = vals[i];
            lp[j] = atomicAdd(&lh[r[j] >> 8], 1);
        }
    }
    __syncthreads();
    for (int j = tid; j < NB; j += 256)
        if (lh[j]) lb[j] = atomicAdd(&gcur[j], lh[j]);
    __syncthreads();
    #pragma unroll
    for (int j = 0; j < EPT; ++j) {
        const int i = base + j * 256 + tid;
        if (i < nnz) {
            int2 e;
            e.x = ((r[j] & 255) << 17) | c[j];
            e.y = __float_as_int(v[j]);
            tmp[lb[r[j] >> 8] + lp[j]] = e;
        }
    }
}

__device__ __forceinline__ void body_vae(int bid, char* smem,
    const float* __restrict__ M, float* __restrict__ Hout,
    const float* __restrict__ EPSN, const u16* __restrict__ WtV,
    const float* __restrict__ mub, const float* __restrict__ lvb,
    float* __restrict__ klslot, int Ntot)
{
    float (*sX)[68] = (float(*)[68])smem;
    float* sC       = (float*)(smem + 17408);
    const int tid = threadIdx.x;
    const int n0 = bid * 64;

    for (int i = tid; i < 64 * 16; i += 256) {
        const int rr = i >> 4, cc = i & 15;
        float4 v = make_float4(0.f, 0.f, 0.f, 0.f);
        if (n0 + rr < Ntot) v = *(const float4*)(M + (size_t)(n0 + rr) * 64 + cc * 4);
        *(float4*)&sX[rr][cc * 4] = v;
    }
    __syncthreads();

    const int w = tid >> 6, l = tid & 63;
    const int m = l & 15, kq = l >> 4;
    const int rowm = w * 16 + m;

    f32x4 zero = {0.f, 0.f, 0.f, 0.f};
    f32x4 acc[8];
    #pragma unroll
    for (int t = 0; t < 8; ++t) acc[t] = zero;

    #pragma unroll
    for (int ks = 0; ks < 2; ++ks) {
        const int k0 = ks * 32 + kq * 8;
        const float4 xa = *(const float4*)&sX[rowm][k0];
        const float4 xb = *(const float4*)&sX[rowm][k0 + 4];
        union { bf16x8 v; u16 u[8]; } af;
        af.u[0] = f2bf(xa.x); af.u[1] = f2bf(xa.y); af.u[2] = f2bf(xa.z); af.u[3] = f2bf(xa.w);
        af.u[4] = f2bf(xb.x); af.u[5] = f2bf(xb.y); af.u[6] = f2bf(xb.z); af.u[7] = f2bf(xb.w);
        #pragma unroll
        for (int t = 0; t < 8; ++t) {
            const bf16x8 bf = *(const bf16x8*)(WtV + (((size_t)(t * 16 + m)) << 6) + k0);
            acc[t] = __builtin_amdgcn_mfma_f32_16x16x32_bf16(af.v, bf, acc[t], 0, 0, 0);
        }
    }

    float klp = 0.f;
    float uv[4][4];
    #pragma unroll
    for (int t = 0; t < 4; ++t) {
        const int col = t * 16 + m;
        const float mb = mub[col], lb = lvb[col];
        #pragma unroll
        for (int r = 0; r < 4; ++r) {
            const int row = w * 16 + kq * 4 + r;
            const float mu = acc[t][r] + mb;
            const float lv = acc[t + 4][r] + lb;
            const float elv = expf(lv);
            float ep = 0.f;
            if (n0 + row < Ntot) {
                klp += 1.0f + lv - mu * mu - elv;
                ep = EPSN[(size_t)(n0 + row) * 64 + col];
            }
            uv[t][r] = mu + ep * expf(0.5f * lv);
        }
    }
    klp = wsum(klp);
    if (l == 0) atomicAdd(&klslot[(bid * 4 + w) & 255], klp);

    #pragma unroll
    for (int t = 0; t < 4; ++t)
        #pragma unroll
        for (int r = 0; r < 4; ++r)
            sX[w * 16 + kq * 4 + r][t * 16 + m] = uv[t][r];
    __syncthreads();

    {
        const int r2 = tid >> 2, j = tid & 3;
        float ss = 0.f;
        #pragma unroll
        for (int jj = 0; jj < 4; ++jj) {
            float4 a = *(const float4*)&sX[r2][j * 16 + jj * 4];
            if (j == 0 && jj == 0) a.x = 0.f;
            ss += a.x * a.x + a.y * a.y + a.z * a.z + a.w * a.w;
        }
        ss += __shfl_xor(ss, 1, 64);
        ss += __shfl_xor(ss, 2, 64);
        if (j == 0) {
            const float nr = fmaxf(sqrtf(ss), EPSF);
            const float r = sinhf(nr) / nr;
            const float sn = r * sqrtf(ss);
            const float scale = fminf(1.0f, MAXNRM / fmaxf(sn, EPSF));
            const float mult = r * scale;
            const float s2 = mult * mult * ss;
            const float z0 = sqrtf(1.0f + s2);
            const float alpha = fmaxf(z0, 1.0f + EPSF);
            const float coef = acoshf(alpha) / sqrtf(fmaxf(alpha * alpha - 1.0f, EPSF));
            sC[r2] = coef * mult;
        }
    }
    __syncthreads();

    for (int i = tid; i < 64 * 16; i += 256) {
        const int rr = i >> 4, cc = i & 15;
        if (n0 + rr >= Ntot) continue;
        const float4 v = *(const float4*)&sX[rr][cc * 4];
        const float sc = sC[rr];
        float4 o;
        o.x = (cc == 0) ? 0.f : sc * v.x;
        o.y = sc * v.y; o.z = sc * v.z; o.w = sc * v.w;
        *(float4*)(Hout + (size_t)(n0 + rr) * 64 + cc * 4) = o;
    }
}

__device__ __forceinline__ void body_sort(int bid, char* smem,
    const int2* __restrict__ tmp, const int* __restrict__ bstart,
    int2* __restrict__ sedge, int* __restrict__ Fout, int Ntot, int nnz)
{
    int* cnt  = (int*)smem;          // RPB ints
    int* excl = cnt + RPB;           // RPB ints
    const int b = bid;
    const int tid = threadIdx.x;
    if (tid < RPB) cnt[tid] = 0;
    __syncthreads();
    const int s = bstart[b], t = bstart[b + 1];

    for (int i = s + tid; i < t; i += 256)
        atomicAdd(&cnt[((unsigned)tmp[i].x) >> 17], 1);
    __syncthreads();

    if (tid < 64) {   // 256-entry exclusive scan: 4 values/lane on wave 0
        const int a0 = cnt[4 * tid], a1 = cnt[4 * tid + 1];
        const int a2 = cnt[4 * tid + 2], a3 = cnt[4 * tid + 3];
        const int tsum = a0 + a1 + a2 + a3;
        int run = tsum;
        #pragma unroll
        for (int off = 1; off < 64; off <<= 1) {
            const int vv = __shfl_up(run, off, 64);
            if (tid >= off) run += vv;
        }
        const int ep = run - tsum;
        excl[4 * tid]     = ep;
        excl[4 * tid + 1] = ep + a0;
        excl[4 * tid + 2] = ep + a0 + a1;
        excl[4 * tid + 3] = ep + a0 + a1 + a2;
    }
    __syncthreads();

    const int r0 = b << 8;
    if (tid < RPB) {
        const int r = r0 + tid;
        if (r < Ntot) Fout[r] = s + excl[tid];
        cnt[tid] = excl[tid];
    }
    if (b == NB - 1 && tid == 0) Fout[Ntot] = nnz;
    __syncthreads();

    for (int i = s + tid; i < t; i += 256) {
        const int2 e = tmp[i];
        const int rib = ((unsigned)e.x) >> 17;
        const int lpos = atomicAdd(&cnt[rib], 1);
        int2 o; o.x = e.x & 0x1FFFF; o.y = e.y;
        sedge[s + lpos] = o;
    }
}

__device__ __forceinline__ void body_recon(int bid, float* sb,
    const float* __restrict__ HM, const float* __restrict__ M,
    int Ntot, float* __restrict__ slot)
{
    const int lane = threadIdx.x & 63;
    const int g = lane >> 4, q = lane & 15;
    const int n = bid * 16 + (threadIdx.x >> 6) * 4 + g;

    float ssh = 0.f, ssm = 0.f, dot = 0.f;
    if (n < Ntot) {
        const float4 h = *(const float4*)(HM + ((size_t)n << 6) + q * 4);
        const float4 m = *(const float4*)(M  + ((size_t)n << 6) + q * 4);
        const float hx = (q == 0) ? 0.f : h.x;
        const float mx = (q == 0) ? 0.f : m.x;
        ssh = hx * hx + h.y * h.y + h.z * h.z + h.w * h.w;
        ssm = mx * mx + m.y * m.y + m.z * m.z + m.w * m.w;
        dot = hx * mx + h.y * m.y + h.z * m.z + h.w * m.w;
    }
    #pragma unroll
    for (int off = 1; off < 16; off <<= 1) {
        ssh += __shfl_xor(ssh, off, 64);
        ssm += __shfl_xor(ssm, off, 64);
        dot += __shfl_xor(dot, off, 64);
    }

    float part = 0.f;
    if (q == 0 && n < Ntot) {
        const float nm = fmaxf(sqrtf(ssm), EPSF);
        const float em0 = coshf(nm);
        const float rm = sinhf(nm) / nm;

        const float nh = fmaxf(sqrtf(ssh), EPSF);
        const float rh = sinhf(nh) / nh;
        const float sn = rh * sqrtf(ssh);
        const float scale = fminf(1.0f, MAXNRM / fmaxf(sn, EPSF));
        const float mult = rh * scale;
        const float rec0 = sqrtf(1.0f + mult * mult * ssh);

        const float inner = mult * rm * dot - rec0 * em0;
        const float dd = acoshf(fmaxf(-inner, 1.0f + EPSF));
        part = dd * dd;
    }
    part = wsum(part);
    if (lane == 0) sb[threadIdx.x >> 6] = part;
    __syncthreads();
    if (threadIdx.x == 0)
        atomicAdd(&slot[bid & 255], sb[0] + sb[1] + sb[2] + sb[3]);
}

__device__ __forceinline__ void body_spmm(int bid,
    const u16* __restrict__ in, u16* __restrict__ outb,
    const int* __restrict__ F, const int2* __restrict__ sedge, int Ntot, int nnz)
{
    const int r = bid * 4 + (threadIdx.x >> 6);
    if (r >= Ntot) return;
    const int lane = threadIdx.x & 63;
    const int g = lane >> 3, q = lane & 7;
    const int e0 = F[r], e1 = F[r + 1];
    const int nnzm1 = nnz - 1;

    float acc0[8], acc1[8];
    #pragma unroll
    for (int j = 0; j < 8; ++j) { acc0[j] = 0.f; acc1[j] = 0.f; }

    int2 edA, edB;
    uint4 hbA, hbB;
    {
        const int ea = e0 + g, eb = e0 + 8 + g;
        edA = sedge[min(ea, nnzm1)]; if (ea >= e1) edA.y = 0;
        edB = sedge[min(eb, nnzm1)]; if (eb >= e1) edB.y = 0;
        hbA = *(const uint4*)(in + (((size_t)edA.x) << 6) + q * 8);
        hbB = *(const uint4*)(in + (((size_t)edB.x) << 6) + q * 8);
    }

    for (int base = e0; base < e1; base += 16) {
        const int na = base + 16 + g, nb = base + 24 + g;
        int2 edA2 = sedge[min(na, nnzm1)]; if (na >= e1) edA2.y = 0;
        int2 edB2 = sedge[min(nb, nnzm1)]; if (nb >= e1) edB2.y = 0;
        const uint4 hbA2 = *(const uint4*)(in + (((size_t)edA2.x) << 6) + q * 8);
        const uint4 hbB2 = *(const uint4*)(in + (((size_t)edB2.x) << 6) + q * 8);

        {
            const float v = __int_as_float(edA.y);
            acc0[0] += v * bflo(hbA.x);
            acc0[1] += v * bfhi(hbA.x);
            acc0[2] += v * bflo(hbA.y);
            acc0[3] += v * bfhi(hbA.y);
            acc0[4] += v * bflo(hbA.z);
            acc0[5] += v * bfhi(hbA.z);
            acc0[6] += v * bflo(hbA.w);
            acc0[7] += v * bfhi(hbA.w);
        }
        {
            const float v = __int_as_float(edB.y);
            acc1[0] += v * bflo(hbB.x);
            acc1[1] += v * bfhi(hbB.x);
            acc1[2] += v * bflo(hbB.y);
            acc1[3] += v * bfhi(hbB.y);
            acc1[4] += v * bflo(hbB.z);
            acc1[5] += v * bfhi(hbB.z);
            acc1[6] += v * bflo(hbB.w);
            acc1[7] += v * bfhi(hbB.w);
        }
        edA = edA2; edB = edB2; hbA = hbA2; hbB = hbB2;
    }
    float a0[8];
    #pragma unroll
    for (int j = 0; j < 8; ++j) a0[j] = acc0[j] + acc1[j];

    #pragma unroll
    for (int off = 8; off < 64; off <<= 1)
        #pragma unroll
        for (int j = 0; j < 8; ++j) a0[j] += __shfl_xor(a0[j], off, 64);

    if (g == 0) {
        const size_t ob = (((size_t)r) << 6) + q * 8;
        uint4 p;
        p.x = (unsigned)f2bf(a0[0]) | ((unsigned)f2bf(a0[1]) << 16);
        p.y = (unsigned)f2bf(a0[2]) | ((unsigned)f2bf(a0[3]) << 16);
        p.z = (unsigned)f2bf(a0[4]) | ((unsigned)f2bf(a0[5]) << 16);
        p.w = (unsigned)f2bf(a0[6]) | ((unsigned)f2bf(a0[7]) << 16);
        *(uint4*)(outb + ob) = p;
    }
}

// ================= fat kernels =================

__global__ __launch_bounds__(256) void fat_prep(
    const float* tW, const float* tb, u16* Wt1, u16* Bt1,
    const float* dW, const float* db, u16* Wt2, u16* Bt2,
    const float* muW, const float* lvW, u16* WtV,
    const float* f1W, u16* Wt1f, const float* f2W, u16* Wt2f)
{
    const int b = blockIdx.x;
    if (b < 36) {
        const float* W = (b < 18) ? tW : dW;
        const float* Bb = (b < 18) ? tb : db;
        u16* Wt = (b < 18) ? Wt1 : Wt2;
        u16* Bt = (b < 18) ? Bt1 : Bt2;
        const int i = (b % 18) * 256 + threadIdx.x;
        if (i < 4096) {
            const int e = i >> 9, o = (i >> 3) & 63, dbi = i & 7;
            u16 v[8];
            #pragma unroll
            for (int j = 0; j < 8; ++j)
                v[j] = f2bf(W[((size_t)e << 12) + (size_t)(dbi * 8 + j) * 64 + o]);
            uint4 p;
            p.x = (unsigned)v[0] | ((unsigned)v[1] << 16);
            p.y = (unsigned)v[2] | ((unsigned)v[3] << 16);
            p.z = (unsigned)v[4] | ((unsigned)v[5] << 16);
            p.w = (unsigned)v[6] | ((unsigned)v[7] << 16);
            *(uint4*)(Wt + (((size_t)(e * 64 + o)) << 6) + dbi * 8) = p;
        } else if (i < 4096 + 512) {
            const int j = i - 4096, o = j >> 3, e = j & 7;
            Bt[o * 8 + e] = f2bf(Bb[e * 64 + o]);
        }
    } else if (b < 68) {
        const bool is_mu = (b < 52);
        const float* src = is_mu ? muW : lvW;
        u16* dst = is_mu ? WtV : (WtV + 4096);
        const int i = ((b - (is_mu ? 36 : 52))) * 256 + threadIdx.x;
        if (i < 4096) {
            const int o = i / 64, k = i - o * 64;
            dst[i] = f2bf(src[k * 64 + o]);
        }
    } else if (b < 100) {
        const int i = (b - 68) * 256 + threadIdx.x;
        if (i < 8192) {
            const int o = i / 64, k = i - o * 64;
            Wt1f[i] = f2bf(f1W[k * 128 + o]);
        }
    } else {
        const int i = (b - 100) * 256 + threadIdx.x;
        if (i < 8192) {
            const int o = i / 128, k = i - o * 128;
            Wt2f[i] = f2bf(f2W[k * 64 + o]);
        }
    }
}

#define NB_LOG 6250
#define NB_HIST 512
__global__ __launch_bounds__(256) void fat_log_bhist(
    const float* eu, const float* ei, int Nu, int Ntot, float* out,
    const int* rows, int nnz, int* bhist)
{
    __shared__ int h[NB];
    const int b = blockIdx.x;
    if (b < NB_LOG) {
        body_logmap(b, eu, ei, Nu, Ntot, out);
    } else {
        body_bhist(b - NB_LOG, NB_HIST, rows, nnz, bhist, h);
    }
}

#define NB_MOE 1563
__global__ __launch_bounds__(256) void fat_moe_bsc(
    const float* X, float* Y, const u16* Wt, const u16* Bt,
    const float* GW, const float* GB, u16* Bhout, int Ntot,
    const int* rows, const int* cols, const float* vals, int nnz,
    int* gcur, int2* tmp)
{
    __shared__ __align__(16) char smem[21504];
    const int b = blockIdx.x;
    if (b < NB_MOE) {
        body_moe(b, smem, X, Y, Wt, Bt, GW, GB, Bhout, Ntot);
    } else {
        body_bscatter(b - NB_MOE, smem, rows, cols, vals, nnz, gcur, tmp);
    }
}

__global__ __launch_bounds__(256) void fat_vae_sort(
    const float* M, float* Hout, const float* EPSN, const u16* WtV,
    const float* mub, const float* lvb, float* klslot, int Ntot,
    const int2* tmp, const int* bstart, int2* sedge, int* Fout, int nnz)
{
    __shared__ __align__(16) char smem[17664];
    const int b = blockIdx.x;
    if (b < NB_MOE) {
        body_vae(b, smem, M, Hout, EPSN, WtV, mub, lvb, klslot, Ntot);
    } else {
        body_sort(b - NB_MOE, smem, tmp, bstart, sedge, Fout, Ntot, nnz);
    }
}

#define NB_SPMM 25000
__global__ __launch_bounds__(256) void fat_recon_spmm(
    const float* HM, const float* M, int Ntot, float* slot,
    const u16* in, u16* outb, const int* F, const int2* sedge, int nnz)
{
    __shared__ float sb[4];
    const int b = blockIdx.x;
    if (b < NB_LOG) {
        body_recon(b, sb, HM, M, Ntot, slot);
    } else {
        body_spmm(b - NB_LOG, in, outb, F, sedge, Ntot, nnz);
    }
}

// ================= standalone kernels =================

__global__ __launch_bounds__(1024) void k_bscan(const int* __restrict__ bhist,
                                                int* __restrict__ bstart, int* __restrict__ gcur) {
    __shared__ int s[1024];
    const int tid = threadIdx.x;
    int v = (tid < NB) ? bhist[tid] : 0;
    s[tid] = v;
    __syncthreads();
    for (int off = 1; off < 1024; off <<= 1) {
        int t = (tid >= off) ? s[tid - off] : 0;
        __syncthreads();
        s[tid] += t;
        __syncthreads();
    }
    if (tid < NB) {
        bstart[tid + 1] = s[tid];
        gcur[tid] = s[tid] - v;
        if (tid == 0) bstart[0] = 0;
    }
}

__global__ __launch_bounds__(256) void k_moe_mfma(
    const float* __restrict__ X, float* __restrict__ Y,
    const u16* __restrict__ Wt, const u16* __restrict__ Bt,
    const float* __restrict__ GW, const float* __restrict__ GB,
    u16* __restrict__ Bhout, int Ntot)
{
    __shared__ __align__(16) char smem[21504];
    body_moe(blockIdx.x, smem, X, Y, Wt, Bt, GW, GB, Bhout, Ntot);
}

__global__ __launch_bounds__(256) void k_ffn_mfma(
    float* __restrict__ Hio,
    const u16* __restrict__ Wt1f, const float* __restrict__ f1b,
    const u16* __restrict__ Wt2f, const float* __restrict__ f2b, int Ntot)
{
    __shared__ float sH[64][68];
    __shared__ u16 sH1[64][136];
    const int tid = threadIdx.x;
    const int n0 = blockIdx.x * 64;

    for (int i = tid; i < 64 * 16; i += 256) {
        const int rr = i >> 4, cc = i & 15;
        float4 v = make_float4(0.f, 0.f, 0.f, 0.f);
        if (n0 + rr < Ntot) v = *(const float4*)(Hio + (size_t)(n0 + rr) * 64 + cc * 4);
        *(float4*)&sH[rr][cc * 4] = v;
    }
    __syncthreads();

    const int w = tid >> 6, l = tid & 63;
    const int m = l & 15, kq = l >> 4;
    const int rowm = w * 16 + m;

    f32x4 zero = {0.f, 0.f, 0.f, 0.f};
    f32x4 acc1[8];
    #pragma unroll
    for (int t = 0; t < 8; ++t) acc1[t] = zero;

    #pragma unroll
    for (int ks = 0; ks < 2; ++ks) {
        const int k0 = ks * 32 + kq * 8;
        const float4 xa = *(const float4*)&sH[rowm][k0];
        const float4 xb = *(const float4*)&sH[rowm][k0 + 4];
        union { bf16x8 v; u16 u[8]; } af;
        af.u[0] = f2bf(xa.x); af.u[1] = f2bf(xa.y); af.u[2] = f2bf(xa.z); af.u[3] = f2bf(xa.w);
        af.u[4] = f2bf(xb.x); af.u[5] = f2bf(xb.y); af.u[6] = f2bf(xb.z); af.u[7] = f2bf(xb.w);
        #pragma unroll
        for (int t = 0; t < 8; ++t) {
            const bf16x8 bf = *(const bf16x8*)(Wt1f + (((size_t)(t * 16 + m)) << 6) + k0);
            acc1[t] = __builtin_amdgcn_mfma_f32_16x16x32_bf16(af.v, bf, acc1[t], 0, 0, 0);
        }
    }
    #pragma unroll
    for (int t = 0; t < 8; ++t) {
        const float bb = f1b[t * 16 + m];
        #pragma unroll
        for (int r = 0; r < 4; ++r)
            sH1[w * 16 + kq * 4 + r][t * 16 + m] = f2bf(fmaxf(acc1[t][r] + bb, 0.f));
    }
    __syncthreads();

    f32x4 acc2[4];
    #pragma unroll
    for (int t = 0; t < 4; ++t) acc2[t] = zero;
    #pragma unroll
    for (int ks = 0; ks < 4; ++ks) {
        const int k0 = ks * 32 + kq * 8;
        const bf16x8 af = *(const bf16x8*)&sH1[rowm][k0];
        #pragma unroll
        for (int t = 0; t < 4; ++t) {
            const bf16x8 bf = *(const bf16x8*)(Wt2f + (((size_t)(t * 16 + m)) << 7) + k0);
            acc2[t] = __builtin_amdgcn_mfma_f32_16x16x32_bf16(af, bf, acc2[t], 0, 0, 0);
        }
    }
    #pragma unroll
    for (int t = 0; t < 4; ++t) {
        const float bb = f2b[t * 16 + m];
        #pragma unroll
        for (int r = 0; r < 4; ++r) {
            const int row = w * 16 + kq * 4 + r;
            if (n0 + row < Ntot)
                Hio[(size_t)(n0 + row) * 64 + t * 16 + m] = acc2[t][r] + bb;
        }
    }
}

__global__ __launch_bounds__(256) void k_spmm(
    const u16* __restrict__ in, u16* __restrict__ outb,
    const int* __restrict__ F, const int2* __restrict__ sedge, int Ntot, int nnz)
{
    body_spmm(blockIdx.x, in, outb, F, sedge, Ntot, nnz);
}

__global__ __launch_bounds__(256) void k_osum(
    const u16* __restrict__ r1, const u16* __restrict__ r2,
    const u16* __restrict__ r3, u16* __restrict__ outb, int Ntot)
{
    const int lane = threadIdx.x & 63;
    const int g = lane >> 4, q = lane & 15;
    const int n = blockIdx.x * 16 + (threadIdx.x >> 6) * 4 + g;
    if (n >= Ntot) return;
    const size_t ob = ((size_t)n << 6) + q * 4;
    const uint2 a = *(const uint2*)(r1 + ob);
    const uint2 b = *(const uint2*)(r2 + ob);
    const uint2 c = *(const uint2*)(r3 + ob);
    float s0 = bflo(a.x) + bflo(b.x) + bflo(c.x);
    float s1 = bfhi(a.x) + bfhi(b.x) + bfhi(c.x);
    float s2 = bflo(a.y) + bflo(b.y) + bflo(c.y);
    float s3 = bfhi(a.y) + bfhi(b.y) + bfhi(c.y);
    const float v0 = (q == 0) ? 0.f : s0;
    float ss = v0 * v0 + s1 * s1 + s2 * s2 + s3 * s3;
    #pragma unroll
    for (int off = 1; off < 16; off <<= 1) ss += __shfl_xor(ss, off, 64);
    const float nr = fmaxf(sqrtf(ss), EPSF);
    const float r = sinhf(nr) / nr;
    const float sn = r * sqrtf(ss);
    const float scale = fminf(1.0f, MAXNRM / fmaxf(sn, EPSF));
    const float mult = r * scale;
    const float o0 = (q == 0) ? sqrtf(1.0f + mult * mult * ss) : mult * s0;
    uint2 p;
    p.x = (unsigned)f2bf(o0) | ((unsigned)f2bf(mult * s1) << 16);
    p.y = (unsigned)f2bf(mult * s2) | ((unsigned)f2bf(mult * s3) << 16);
    *(uint2*)(outb + ob) = p;
}

__global__ __launch_bounds__(256) void k_triples(
    const u16* __restrict__ Ob, const int* __restrict__ tri,
    int T, float* __restrict__ slot)
{
    const int lane = threadIdx.x & 63;
    const int g = lane >> 4, q = lane & 15;
    const int wid = blockIdx.x * 4 + (threadIdx.x >> 6);
    const int stride = gridDim.x * 4 * 4;

    float racc = 0.f;
    int t = wid * 4 + g;

    uint2 ca, cp, cn;
    if (t < T) {
        const int a = tri[3 * t], p = tri[3 * t + 1], nn = tri[3 * t + 2];
        ca = *(const uint2*)(Ob + (((size_t)a) << 6) + q * 4);
        cp = *(const uint2*)(Ob + (((size_t)p) << 6) + q * 4);
        cn = *(const uint2*)(Ob + (((size_t)nn) << 6) + q * 4);
    }

    for (; t < T; ) {
        const int tn = t + stride;
        const int tc = min(tn, T - 1);
        const int a2 = tri[3 * tc], p2 = tri[3 * tc + 1], n2 = tri[3 * tc + 2];
        const uint2 na_ = *(const uint2*)(Ob + (((size_t)a2) << 6) + q * 4);
        const uint2 np_ = *(const uint2*)(Ob + (((size_t)p2) << 6) + q * 4);
        const uint2 nn_ = *(const uint2*)(Ob + (((size_t)n2) << 6) + q * 4);

        {
            const float a0 = bflo(ca.x), a1 = bfhi(ca.x), a2f = bflo(ca.y), a3 = bfhi(ca.y);
            const float p0 = bflo(cp.x), p1 = bfhi(cp.x), p2f = bflo(cp.y), p3 = bfhi(cp.y);
            const float n0 = bflo(cn.x), n1 = bfhi(cn.x), n2f = bflo(cn.y), n3 = bfhi(cn.y);
            const float s0 = (q == 0) ? -1.f : 1.f;
            float i1 = s0 * a0 * p0 + a1 * p1 + a2f * p2f + a3 * p3;
            float i2 = s0 * a0 * n0 + a1 * n1 + a2f * n2f + a3 * n3;
            #pragma unroll
            for (int off = 1; off < 16; off <<= 1) {
                i1 += __shfl_xor(i1, off, 64);
                i2 += __shfl_xor(i2, off, 64);
            }
            if (q == 0) {
                const float d1 = acoshf(fmaxf(-i1, 1.0f + EPSF));
                const float d2 = acoshf(fmaxf(-i2, 1.0f + EPSF));
                const float l = d1 * d1 - d2 * d2 + 0.1f;
                if (l > 0.f) racc += l;
            }
        }
        ca = na_; cp = np_; cn = nn_;
        t = tn;
    }

    racc = wsum(racc);
    __shared__ float sb[4];
    if (lane == 0) sb[threadIdx.x >> 6] = racc;
    __syncthreads();
    if (threadIdx.x == 0)
        atomicAdd(&slot[blockIdx.x & 255], sb[0] + sb[1] + sb[2] + sb[3]);
}

__global__ void k_final(const float* __restrict__ slots, float* __restrict__ out, int Ntot)
{
    const int tid = threadIdx.x;
    float m = slots[tid], r = slots[256 + tid], k = slots[512 + tid];
    m = wsum(m); r = wsum(r); k = wsum(k);
    __shared__ float sm[4], sr[4], sk[4];
    if ((tid & 63) == 0) { sm[tid >> 6] = m; sr[tid >> 6] = r; sk[tid >> 6] = k; }
    __syncthreads();
    if (tid == 0) {
        const float M = sm[0] + sm[1] + sm[2] + sm[3];
        const float R = sr[0] + sr[1] + sr[2] + sr[3];
        const float K = sk[0] + sk[1] + sk[2] + sk[3];
        const float recon = R / (float)Ntot;
        const float kl = -0.5f * K / ((float)Ntot * 64.0f);
        out[0] = M + 0.1f * (recon + kl);
    }
}

extern "C" void kernel_launch(void* const* d_in, const int* in_sizes, int n_in,
                              void* d_out, int out_size, void* d_ws, size_t ws_size,
                              hipStream_t stream)
{
    const float* emb_user = (const float*)d_in[0];
    const float* emb_item = (const float*)d_in[1];
    const int*   adj_rows = (const int*)d_in[2];
    const int*   adj_cols = (const int*)d_in[3];
    const float* adj_vals = (const float*)d_in[4];
    const int*   triples  = (const int*)d_in[5];
    const float* epsin    = (const float*)d_in[6];
    const float* tW  = (const float*)d_in[7];
    const float* tb  = (const float*)d_in[8];
    const float* tgW = (const float*)d_in[9];
    const float* tgb = (const float*)d_in[10];
    const float* muW = (const float*)d_in[11];
    const float* mub = (const float*)d_in[12];
    const float* lvW = (const float*)d_in[13];
    const float* lvb = (const float*)d_in[14];
    const float* f1W = (const float*)d_in[15];
    const float* f1b = (const float*)d_in[16];
    const float* f2W = (const float*)d_in[17];
    const float* f2b = (const float*)d_in[18];
    const float* dW  = (const float*)d_in[19];
    const float* db  = (const float*)d_in[20];
    const float* dgW = (const float*)d_in[21];
    const float* dgb = (const float*)d_in[22];

    const int Nu = in_sizes[0] / 64, Ni = in_sizes[1] / 64;
    const int N = Nu + Ni;            // 100000
    const int NNZ = in_sizes[4];      // 3200000
    const int T = in_sizes[5] / 3;    // 262144

    float* ws = (float*)d_ws;
    size_t off = 0;
    float* slots = ws + off; off += 1024;            // margin / recon / kl slots
    float* A  = ws + off; off += (size_t)N * 64;     // t -> h; later Hb3 bf16
    float* B  = ws + off; off += (size_t)N * 64;     // m fp32 ; later Ob bf16
    float* C  = ws + off; off += (size_t)N * 64;     // tmp int2; then hm fp32
    float* D  = ws + off; off += (size_t)N * 64;     // sedge (CSR int2[NNZ])
    float* E  = ws + off; off += (size_t)N * 64;     // Bh (-> Hb2) + Hb1 (bf16)
    int*   F  = (int*)(ws + off); off += (size_t)N + 64;   // row starts
    int*   bstart = (int*)(ws + off); off += 1024;
    int*   bhist  = (int*)(ws + off); off += 1024;
    int*   gcur   = (int*)(ws + off); off += 1024;
    u16* Wt1 = (u16*)(ws + off); off += 16384;  // MoE1 8x64x64
    u16* Bt1 = (u16*)(ws + off); off += 256;
    u16* Wt2 = (u16*)(ws + off); off += 16384;  // MoE2
    u16* Bt2 = (u16*)(ws + off); off += 256;
    u16* WtV  = (u16*)(ws + off); off += 4096;  // [mu|lv] 128x64
    u16* Wt1f = (u16*)(ws + off); off += 4096;  // f1W^T 128x64
    u16* Wt2f = (u16*)(ws + off); off += 4096;  // f2W^T 64x128

    int2* tmp   = (int2*)C;                     // C free until moe2 (sort consumes tmp first)
    int2* sedge = (int2*)D;
    u16* Bh  = (u16*)E;                         // dead after spmm1
    u16* Hb1 = (u16*)E + (size_t)N * 64;
    u16* Hb2 = (u16*)E;                         // reuses Bh region (spmm2 output)
    u16* Hb3 = (u16*)A;                         // after moe2 consumed A
    u16* Ob  = (u16*)B;                         // after recon read B

    hipMemsetAsync(slots, 0, 1024 * sizeof(float), stream);
    hipMemsetAsync(bhist, 0, 1024 * sizeof(int), stream);

    const int nb16 = (N + 15) / 16;   // 6250 (== NB_LOG)
    const int nb64 = (N + 63) / 64;   // 1563 (== NB_MOE)
    const int nbN4 = (N + 3) / 4;     // 25000 (== NB_SPMM)
    const int ns1 = (NNZ + 256 * EPT - 1) / (256 * EPT);   // 782 scatter blocks

    // 1. all weight prep in one launch
    fat_prep<<<132, 256, 0, stream>>>(tW, tb, Wt1, Bt1, dW, db, Wt2, Bt2,
                                      muW, lvW, WtV, f1W, Wt1f, f2W, Wt2f);

    // 2. logmap (A) || bhist
    fat_log_bhist<<<NB_LOG + NB_HIST, 256, 0, stream>>>(emb_user, emb_item, Nu, N, A,
                                                        adj_rows, NNZ, bhist);

    // 3. bucket scan
    k_bscan<<<1, 1024, 0, stream>>>(bhist, bstart, gcur);

    // 4. moe1 (A->B, Bh) || bscatter (-> tmp=C)
    fat_moe_bsc<<<NB_MOE + ns1, 256, 0, stream>>>(A, B, Wt1, Bt1, tgW, tgb, Bh, N,
                                                  adj_rows, adj_cols, adj_vals, NNZ, gcur, tmp);

    // 5. vae (B->A) || sort (tmp=C -> sedge=D, F)
    fat_vae_sort<<<NB_MOE + NB, 256, 0, stream>>>(B, A, epsin, WtV, mub, lvb, slots + 512, N,
                                                  tmp, bstart, sedge, F, NNZ);

    // 6-7. ffn (A in place), moe2 (A -> C)
    k_ffn_mfma<<<nb64, 256, 0, stream>>>(A, Wt1f, f1b, Wt2f, f2b, N);
    k_moe_mfma<<<nb64, 256, 0, stream>>>(A, C, Wt2, Bt2, dgW, dgb, (u16*)0, N);

    // 8-9. spmm1, spmm2 (standalone, full occupancy)
    k_spmm<<<nbN4, 256, 0, stream>>>(Bh,  Hb1, F, sedge, N, NNZ);
    k_spmm<<<nbN4, 256, 0, stream>>>(Hb1, Hb2, F, sedge, N, NNZ);

    // 10. recon (C,B) || spmm3 (Hb2 -> Hb3 = A) — both lean bodies
    fat_recon_spmm<<<NB_LOG + NB_SPMM, 256, 0, stream>>>(C, B, N, slots + 256,
                                                         Hb2, Hb3, F, sedge, NNZ);

    // 11. out_sum + expmap
    k_osum<<<nb16, 256, 0, stream>>>(Hb1, Hb2, Hb3, Ob, N);

    k_triples<<<2048, 256, 0, stream>>>(Ob, triples, T, slots);
    k_final<<<1, 256, 0, stream>>>(slots, (float*)d_out, N);
}

// Round 23
// 453.694 us; speedup vs baseline: 1.0110x; 1.0110x over previous
//
#include <hip/hip_runtime.h>
#include <math.h>

#define EPSF 1e-7f
#define MAXNRM 10.0f
#define NB 782          // ceil(100000/128) buckets
#define RPB 128         // rows per bucket
#define EPT 16          // edges per thread in stage-1 scatter

using bf16x8 = __attribute__((ext_vector_type(8))) short;
using f32x4  = __attribute__((ext_vector_type(4))) float;
typedef unsigned short u16;

__device__ __forceinline__ float wsum(float v) {
    #pragma unroll
    for (int off = 32; off > 0; off >>= 1) v += __shfl_xor(v, off, 64);
    return v;
}

__device__ __forceinline__ u16 f2bf(float x) {   // RNE
    unsigned u = __float_as_uint(x);
    unsigned r = (u + 0x7FFFu + ((u >> 16) & 1u)) >> 16;
    return (u16)r;
}
__device__ __forceinline__ float bflo(unsigned u) { return __uint_as_float(u << 16); }
__device__ __forceinline__ float bfhi(unsigned u) { return __uint_as_float(u & 0xFFFF0000u); }

// ================= bodies =================

__device__ __forceinline__ void body_logmap(int bid, const float* __restrict__ eu,
                                            const float* __restrict__ ei, int Nu, int Ntot,
                                            float* __restrict__ out) {
    const int lane = threadIdx.x & 63;
    const int g = lane >> 4, q = lane & 15;
    const int n = bid * 16 + (threadIdx.x >> 6) * 4 + g;
    if (n >= Ntot) return;
    const float* src = (n < Nu) ? (eu + (size_t)n * 64) : (ei + (size_t)(n - Nu) * 64);
    const float x0 = src[0];
    const float alpha = fmaxf(x0, 1.0f + EPSF);
    const float coef = acoshf(alpha) / sqrtf(fmaxf(alpha * alpha - 1.0f, EPSF));
    const float4 v = *(const float4*)(src + q * 4);
    float4 o;
    o.x = (q == 0) ? 0.0f : coef * v.x;
    o.y = coef * v.y; o.z = coef * v.z; o.w = coef * v.w;
    *(float4*)(out + ((size_t)n << 6) + q * 4) = o;
}

__device__ __forceinline__ void body_bhist(int bid, int nblk, const int* __restrict__ rows,
                                           int nnz, int* __restrict__ bhist, int* h) {
    for (int j = threadIdx.x; j < NB; j += 256) h[j] = 0;
    __syncthreads();
    for (int i = bid * 256 + threadIdx.x; i < nnz; i += nblk * 256)
        atomicAdd(&h[rows[i] >> 7], 1);
    __syncthreads();
    for (int j = threadIdx.x; j < NB; j += 256)
        if (h[j]) atomicAdd(&bhist[j], h[j]);
}

__device__ __forceinline__ void body_prep(int b,
    const float* __restrict__ tW, const float* __restrict__ tb, u16* __restrict__ Wt1, u16* __restrict__ Bt1,
    const float* __restrict__ dW, const float* __restrict__ db, u16* __restrict__ Wt2, u16* __restrict__ Bt2,
    const float* __restrict__ muW, const float* __restrict__ lvW, u16* __restrict__ WtV,
    const float* __restrict__ f1W, u16* __restrict__ Wt1f, const float* __restrict__ f2W, u16* __restrict__ Wt2f)
{
    if (b < 36) {
        const float* W = (b < 18) ? tW : dW;
        const float* Bb = (b < 18) ? tb : db;
        u16* Wt = (b < 18) ? Wt1 : Wt2;
        u16* Bt = (b < 18) ? Bt1 : Bt2;
        const int i = (b % 18) * 256 + threadIdx.x;
        if (i < 4096) {
            const int e = i >> 9, o = (i >> 3) & 63, dbi = i & 7;
            u16 v[8];
            #pragma unroll
            for (int j = 0; j < 8; ++j)
                v[j] = f2bf(W[((size_t)e << 12) + (size_t)(dbi * 8 + j) * 64 + o]);
            uint4 p;
            p.x = (unsigned)v[0] | ((unsigned)v[1] << 16);
            p.y = (unsigned)v[2] | ((unsigned)v[3] << 16);
            p.z = (unsigned)v[4] | ((unsigned)v[5] << 16);
            p.w = (unsigned)v[6] | ((unsigned)v[7] << 16);
            *(uint4*)(Wt + (((size_t)(e * 64 + o)) << 6) + dbi * 8) = p;
        } else if (i < 4096 + 512) {
            const int j = i - 4096, o = j >> 3, e = j & 7;
            Bt[o * 8 + e] = f2bf(Bb[e * 64 + o]);
        }
    } else if (b < 68) {
        const bool is_mu = (b < 52);
        const float* src = is_mu ? muW : lvW;
        u16* dst = is_mu ? WtV : (WtV + 4096);
        const int i = ((b - (is_mu ? 36 : 52))) * 256 + threadIdx.x;
        if (i < 4096) {
            const int o = i / 64, k = i - o * 64;
            dst[i] = f2bf(src[k * 64 + o]);
        }
    } else if (b < 100) {
        const int i = (b - 68) * 256 + threadIdx.x;
        if (i < 8192) {
            const int o = i / 64, k = i - o * 64;
            Wt1f[i] = f2bf(f1W[k * 128 + o]);
        }
    } else {
        const int i = (b - 100) * 256 + threadIdx.x;
        if (i < 8192) {
            const int o = i / 128, k = i - o * 128;
            Wt2f[i] = f2bf(f2W[k * 64 + o]);
        }
    }
}

__device__ __forceinline__ void body_moe(int bid, char* smem,
    const float* __restrict__ X, float* __restrict__ Y,
    const u16* __restrict__ Wt, const u16* __restrict__ Bt,
    const float* __restrict__ GW, const float* __restrict__ GB,
    u16* __restrict__ Bhout, int Ntot)
{
    float (*sX)[68] = (float(*)[68])smem;
    float (*sG)[8]  = (float(*)[8])(smem + 17408);
    float* sGW      = (float*)(smem + 17408 + 2048);
    const int tid = threadIdx.x;
    const int n0 = bid * 64;

    for (int i = tid; i < 64 * 16; i += 256) {
        const int rr = i >> 4, cc = i & 15;
        float4 v = make_float4(0.f, 0.f, 0.f, 0.f);
        if (n0 + rr < Ntot) v = *(const float4*)(X + (size_t)(n0 + rr) * 64 + cc * 4);
        *(float4*)&sX[rr][cc * 4] = v;
    }
    for (int i = tid; i < 512; i += 256) sGW[i] = GW[i];
    __syncthreads();

    {
        const int n = tid >> 2, e0 = (tid & 3) * 2;
        float lg0 = GB[e0], lg1 = GB[e0 + 1];
        #pragma unroll 8
        for (int d = 0; d < 64; ++d) {
            const float xv = sX[n][d];
            lg0 += xv * sGW[d * 8 + e0];
            lg1 += xv * sGW[d * 8 + e0 + 1];
        }
        sG[n][e0] = lg0; sG[n][e0 + 1] = lg1;
    }
    __syncthreads();
    if (tid < 64) {
        float ex[8], mx = -1e30f, s = 0.f;
        #pragma unroll
        for (int e = 0; e < 8; ++e) mx = fmaxf(mx, sG[tid][e]);
        #pragma unroll
        for (int e = 0; e < 8; ++e) { ex[e] = expf(sG[tid][e] - mx); s += ex[e]; }
        const float inv = 1.0f / s;
        #pragma unroll
        for (int e = 0; e < 8; ++e) sG[tid][e] = ex[e] * inv;
    }
    __syncthreads();

    const int w = tid >> 6, l = tid & 63;
    const int m = l & 15, kq = l >> 4;
    const int col = w * 16 + m;

    f32x4 zero = {0.f, 0.f, 0.f, 0.f};
    f32x4 acc[4];
    #pragma unroll
    for (int rt = 0; rt < 4; ++rt) acc[rt] = zero;

    bf16x8 bcur = *(const bf16x8*)(Wt + (((size_t)col) << 6) + kq * 8);

    #pragma unroll
    for (int kk = 0; kk < 16; ++kk) {
        const int e = kk >> 1;
        const int d0 = (kk & 1) * 32 + kq * 8;
        bf16x8 bnext = bcur;
        if (kk < 15) {
            const int e2 = (kk + 1) >> 1;
            const int d02 = ((kk + 1) & 1) * 32 + kq * 8;
            bnext = *(const bf16x8*)(Wt + (((size_t)(e2 * 64 + col)) << 6) + d02);
        }
        #pragma unroll
        for (int rt = 0; rt < 4; ++rt) {
            const int row = rt * 16 + m;
            const float gme = sG[row][e];
            const float4 xa = *(const float4*)&sX[row][d0];
            const float4 xb = *(const float4*)&sX[row][d0 + 4];
            union { bf16x8 v; u16 u[8]; } af;
            af.u[0] = f2bf(gme * xa.x); af.u[1] = f2bf(gme * xa.y);
            af.u[2] = f2bf(gme * xa.z); af.u[3] = f2bf(gme * xa.w);
            af.u[4] = f2bf(gme * xb.x); af.u[5] = f2bf(gme * xb.y);
            af.u[6] = f2bf(gme * xb.z); af.u[7] = f2bf(gme * xb.w);
            acc[rt] = __builtin_amdgcn_mfma_f32_16x16x32_bf16(af.v, bcur, acc[rt], 0, 0, 0);
        }
        bcur = bnext;
    }
    {
        bf16x8 z8 = {0, 0, 0, 0, 0, 0, 0, 0};
        bf16x8 bb = z8;
        if (kq == 0) bb = *(const bf16x8*)(Bt + (col << 3));
        #pragma unroll
        for (int rt = 0; rt < 4; ++rt) {
            union { bf16x8 v; u16 u[8]; } af;
            #pragma unroll
            for (int j = 0; j < 8; ++j)
                af.u[j] = (kq == 0) ? f2bf(sG[rt * 16 + m][j]) : (u16)0;
            acc[rt] = __builtin_amdgcn_mfma_f32_16x16x32_bf16(af.v, bb, acc[rt], 0, 0, 0);
        }
    }

    #pragma unroll
    for (int rt = 0; rt < 4; ++rt) {
        #pragma unroll
        for (int r = 0; r < 4; ++r) {
            const int row = rt * 16 + kq * 4 + r;
            if (n0 + row < Ntot) {
                Y[(size_t)(n0 + row) * 64 + col] = acc[rt][r];
                if (Bhout)
                    Bhout[(((size_t)(n0 + row)) << 6) + col] = f2bf(acc[rt][r]);
            }
        }
    }
}

__device__ __forceinline__ void body_bscatter(int bid, char* smem,
    const int* __restrict__ rows, const int* __restrict__ cols,
    const float* __restrict__ vals, int nnz,
    int* __restrict__ gcur, int2* __restrict__ tmp)
{
    int* lh = (int*)smem;
    int* lb = (int*)(smem + 3128);
    const int tid = threadIdx.x;
    for (int j = tid; j < NB; j += 256) lh[j] = 0;
    __syncthreads();

    const int base = bid * (256 * EPT);
    int r[EPT], c[EPT], lp[EPT];
    float v[EPT];
    #pragma unroll
    for (int j = 0; j < EPT; ++j) {
        const int i = base + j * 256 + tid;
        if (i < nnz) {
            r[j] = rows[i]; c[j] = cols[i]; v[j] = vals[i];
            lp[j] = atomicAdd(&lh[r[j] >> 7], 1);
        }
    }
    __syncthreads();
    for (int j = tid; j < NB; j += 256)
        if (lh[j]) lb[j] = atomicAdd(&gcur[j], lh[j]);
    __syncthreads();
    #pragma unroll
    for (int j = 0; j < EPT; ++j) {
        const int i = base + j * 256 + tid;
        if (i < nnz) {
            int2 e;
            e.x = ((r[j] & 127) << 17) | c[j];
            e.y = __float_as_int(v[j]);
            tmp[lb[r[j] >> 7] + lp[j]] = e;
        }
    }
}

__device__ __forceinline__ void body_vae(int bid, char* smem,
    const float* __restrict__ M, float* __restrict__ Hout,
    const float* __restrict__ EPSN, const u16* __restrict__ WtV,
    const float* __restrict__ mub, const float* __restrict__ lvb,
    float* __restrict__ klslot, int Ntot)
{
    float (*sX)[68] = (float(*)[68])smem;
    float* sC       = (float*)(smem + 17408);
    const int tid = threadIdx.x;
    const int n0 = bid * 64;

    for (int i = tid; i < 64 * 16; i += 256) {
        const int rr = i >> 4, cc = i & 15;
        float4 v = make_float4(0.f, 0.f, 0.f, 0.f);
        if (n0 + rr < Ntot) v = *(const float4*)(M + (size_t)(n0 + rr) * 64 + cc * 4);
        *(float4*)&sX[rr][cc * 4] = v;
    }
    __syncthreads();

    const int w = tid >> 6, l = tid & 63;
    const int m = l & 15, kq = l >> 4;
    const int rowm = w * 16 + m;

    f32x4 zero = {0.f, 0.f, 0.f, 0.f};
    f32x4 acc[8];
    #pragma unroll
    for (int t = 0; t < 8; ++t) acc[t] = zero;

    #pragma unroll
    for (int ks = 0; ks < 2; ++ks) {
        const int k0 = ks * 32 + kq * 8;
        const float4 xa = *(const float4*)&sX[rowm][k0];
        const float4 xb = *(const float4*)&sX[rowm][k0 + 4];
        union { bf16x8 v; u16 u[8]; } af;
        af.u[0] = f2bf(xa.x); af.u[1] = f2bf(xa.y); af.u[2] = f2bf(xa.z); af.u[3] = f2bf(xa.w);
        af.u[4] = f2bf(xb.x); af.u[5] = f2bf(xb.y); af.u[6] = f2bf(xb.z); af.u[7] = f2bf(xb.w);
        #pragma unroll
        for (int t = 0; t < 8; ++t) {
            const bf16x8 bf = *(const bf16x8*)(WtV + (((size_t)(t * 16 + m)) << 6) + k0);
            acc[t] = __builtin_amdgcn_mfma_f32_16x16x32_bf16(af.v, bf, acc[t], 0, 0, 0);
        }
    }

    float klp = 0.f;
    float uv[4][4];
    #pragma unroll
    for (int t = 0; t < 4; ++t) {
        const int col = t * 16 + m;
        const float mb = mub[col], lb = lvb[col];
        #pragma unroll
        for (int r = 0; r < 4; ++r) {
            const int row = w * 16 + kq * 4 + r;
            const float mu = acc[t][r] + mb;
            const float lv = acc[t + 4][r] + lb;
            const float elv = expf(lv);
            float ep = 0.f;
            if (n0 + row < Ntot) {
                klp += 1.0f + lv - mu * mu - elv;
                ep = EPSN[(size_t)(n0 + row) * 64 + col];
            }
            uv[t][r] = mu + ep * expf(0.5f * lv);
        }
    }
    klp = wsum(klp);
    if (l == 0) atomicAdd(&klslot[(bid * 4 + w) & 255], klp);

    #pragma unroll
    for (int t = 0; t < 4; ++t)
        #pragma unroll
        for (int r = 0; r < 4; ++r)
            sX[w * 16 + kq * 4 + r][t * 16 + m] = uv[t][r];
    __syncthreads();

    {
        const int r2 = tid >> 2, j = tid & 3;
        float ss = 0.f;
        #pragma unroll
        for (int jj = 0; jj < 4; ++jj) {
            float4 a = *(const float4*)&sX[r2][j * 16 + jj * 4];
            if (j == 0 && jj == 0) a.x = 0.f;
            ss += a.x * a.x + a.y * a.y + a.z * a.z + a.w * a.w;
        }
        ss += __shfl_xor(ss, 1, 64);
        ss += __shfl_xor(ss, 2, 64);
        if (j == 0) {
            const float nr = fmaxf(sqrtf(ss), EPSF);
            const float r = sinhf(nr) / nr;
            const float sn = r * sqrtf(ss);
            const float scale = fminf(1.0f, MAXNRM / fmaxf(sn, EPSF));
            const float mult = r * scale;
            const float s2 = mult * mult * ss;
            const float z0 = sqrtf(1.0f + s2);
            const float alpha = fmaxf(z0, 1.0f + EPSF);
            const float coef = acoshf(alpha) / sqrtf(fmaxf(alpha * alpha - 1.0f, EPSF));
            sC[r2] = coef * mult;
        }
    }
    __syncthreads();

    for (int i = tid; i < 64 * 16; i += 256) {
        const int rr = i >> 4, cc = i & 15;
        if (n0 + rr >= Ntot) continue;
        const float4 v = *(const float4*)&sX[rr][cc * 4];
        const float sc = sC[rr];
        float4 o;
        o.x = (cc == 0) ? 0.f : sc * v.x;
        o.y = sc * v.y; o.z = sc * v.z; o.w = sc * v.w;
        *(float4*)(Hout + (size_t)(n0 + rr) * 64 + cc * 4) = o;
    }
}

__device__ __forceinline__ void body_sort(int bid, char* smem,
    const int2* __restrict__ tmp, const int* __restrict__ bstart,
    int2* __restrict__ sedge, int* __restrict__ Fout, int Ntot, int nnz)
{
    int* cnt  = (int*)smem;
    int* excl = (int*)(smem + 512);
    const int b = bid;
    const int tid = threadIdx.x;
    if (tid < RPB) cnt[tid] = 0;
    __syncthreads();
    const int s = bstart[b], t = bstart[b + 1];

    for (int i = s + tid; i < t; i += 256)
        atomicAdd(&cnt[((unsigned)tmp[i].x) >> 17], 1);
    __syncthreads();

    if (tid < 64) {
        const int a0 = cnt[2 * tid], a1 = cnt[2 * tid + 1];
        const int pairsum = a0 + a1;
        int run = pairsum;
        #pragma unroll
        for (int off = 1; off < 64; off <<= 1) {
            const int vv = __shfl_up(run, off, 64);
            if (tid >= off) run += vv;
        }
        const int ep = run - pairsum;
        excl[2 * tid] = ep;
        excl[2 * tid + 1] = ep + a0;
    }
    __syncthreads();

    const int r0 = b << 7;
    if (tid < RPB) {
        const int r = r0 + tid;
        if (r < Ntot) Fout[r] = s + excl[tid];
        cnt[tid] = excl[tid];
    }
    if (b == NB - 1 && tid == 0) Fout[Ntot] = nnz;
    __syncthreads();

    for (int i = s + tid; i < t; i += 256) {
        const int2 e = tmp[i];
        const int rib = ((unsigned)e.x) >> 17;
        const int lpos = atomicAdd(&cnt[rib], 1);
        int2 o; o.x = e.x & 0x1FFFF; o.y = e.y;
        sedge[s + lpos] = o;
    }
}

__device__ __forceinline__ void body_recon(int bid, float* sb,
    const float* __restrict__ HM, const float* __restrict__ M,
    int Ntot, float* __restrict__ slot)
{
    const int lane = threadIdx.x & 63;
    const int g = lane >> 4, q = lane & 15;
    const int n = bid * 16 + (threadIdx.x >> 6) * 4 + g;

    float ssh = 0.f, ssm = 0.f, dot = 0.f;
    if (n < Ntot) {
        const float4 h = *(const float4*)(HM + ((size_t)n << 6) + q * 4);
        const float4 m = *(const float4*)(M  + ((size_t)n << 6) + q * 4);
        const float hx = (q == 0) ? 0.f : h.x;
        const float mx = (q == 0) ? 0.f : m.x;
        ssh = hx * hx + h.y * h.y + h.z * h.z + h.w * h.w;
        ssm = mx * mx + m.y * m.y + m.z * m.z + m.w * m.w;
        dot = hx * mx + h.y * m.y + h.z * m.z + h.w * m.w;
    }
    #pragma unroll
    for (int off = 1; off < 16; off <<= 1) {
        ssh += __shfl_xor(ssh, off, 64);
        ssm += __shfl_xor(ssm, off, 64);
        dot += __shfl_xor(dot, off, 64);
    }

    float part = 0.f;
    if (q == 0 && n < Ntot) {
        const float nm = fmaxf(sqrtf(ssm), EPSF);
        const float em0 = coshf(nm);
        const float rm = sinhf(nm) / nm;

        const float nh = fmaxf(sqrtf(ssh), EPSF);
        const float rh = sinhf(nh) / nh;
        const float sn = rh * sqrtf(ssh);
        const float scale = fminf(1.0f, MAXNRM / fmaxf(sn, EPSF));
        const float mult = rh * scale;
        const float rec0 = sqrtf(1.0f + mult * mult * ssh);

        const float inner = mult * rm * dot - rec0 * em0;
        const float dd = acoshf(fmaxf(-inner, 1.0f + EPSF));
        part = dd * dd;
    }
    part = wsum(part);
    if (lane == 0) sb[threadIdx.x >> 6] = part;
    __syncthreads();
    if (threadIdx.x == 0)
        atomicAdd(&slot[bid & 255], sb[0] + sb[1] + sb[2] + sb[3]);
}

__device__ __forceinline__ void body_spmm(int bid,
    const u16* __restrict__ in, u16* __restrict__ outb,
    const int* __restrict__ F, const int2* __restrict__ sedge, int Ntot, int nnz)
{
    const int r = bid * 4 + (threadIdx.x >> 6);
    if (r >= Ntot) return;
    const int lane = threadIdx.x & 63;
    const int g = lane >> 3, q = lane & 7;
    const int e0 = F[r], e1 = F[r + 1];
    const int nnzm1 = nnz - 1;

    float acc0[8], acc1[8];
    #pragma unroll
    for (int j = 0; j < 8; ++j) { acc0[j] = 0.f; acc1[j] = 0.f; }

    int2 edA, edB;
    uint4 hbA, hbB;
    {
        const int ea = e0 + g, eb = e0 + 8 + g;
        edA = sedge[min(ea, nnzm1)]; if (ea >= e1) edA.y = 0;
        edB = sedge[min(eb, nnzm1)]; if (eb >= e1) edB.y = 0;
        hbA = *(const uint4*)(in + (((size_t)edA.x) << 6) + q * 8);
        hbB = *(const uint4*)(in + (((size_t)edB.x) << 6) + q * 8);
    }

    for (int base = e0; base < e1; base += 16) {
        const int na = base + 16 + g, nb = base + 24 + g;
        int2 edA2 = sedge[min(na, nnzm1)]; if (na >= e1) edA2.y = 0;
        int2 edB2 = sedge[min(nb, nnzm1)]; if (nb >= e1) edB2.y = 0;
        const uint4 hbA2 = *(const uint4*)(in + (((size_t)edA2.x) << 6) + q * 8);
        const uint4 hbB2 = *(const uint4*)(in + (((size_t)edB2.x) << 6) + q * 8);

        {
            const float v = __int_as_float(edA.y);
            acc0[0] += v * bflo(hbA.x);
            acc0[1] += v * bfhi(hbA.x);
            acc0[2] += v * bflo(hbA.y);
            acc0[3] += v * bfhi(hbA.y);
            acc0[4] += v * bflo(hbA.z);
            acc0[5] += v * bfhi(hbA.z);
            acc0[6] += v * bflo(hbA.w);
            acc0[7] += v * bfhi(hbA.w);
        }
        {
            const float v = __int_as_float(edB.y);
            acc1[0] += v * bflo(hbB.x);
            acc1[1] += v * bfhi(hbB.x);
            acc1[2] += v * bflo(hbB.y);
            acc1[3] += v * bfhi(hbB.y);
            acc1[4] += v * bflo(hbB.z);
            acc1[5] += v * bfhi(hbB.z);
            acc1[6] += v * bflo(hbB.w);
            acc1[7] += v * bfhi(hbB.w);
        }
        edA = edA2; edB = edB2; hbA = hbA2; hbB = hbB2;
    }
    float a0[8];
    #pragma unroll
    for (int j = 0; j < 8; ++j) a0[j] = acc0[j] + acc1[j];

    #pragma unroll
    for (int off = 8; off < 64; off <<= 1)
        #pragma unroll
        for (int j = 0; j < 8; ++j) a0[j] += __shfl_xor(a0[j], off, 64);

    if (g == 0) {
        const size_t ob = (((size_t)r) << 6) + q * 8;
        uint4 p;
        p.x = (unsigned)f2bf(a0[0]) | ((unsigned)f2bf(a0[1]) << 16);
        p.y = (unsigned)f2bf(a0[2]) | ((unsigned)f2bf(a0[3]) << 16);
        p.z = (unsigned)f2bf(a0[4]) | ((unsigned)f2bf(a0[5]) << 16);
        p.w = (unsigned)f2bf(a0[6]) | ((unsigned)f2bf(a0[7]) << 16);
        *(uint4*)(outb + ob) = p;
    }
}

// ================= fat kernels =================

#define NB_LOG 6250
#define NB_HIST 512
#define NB_PREP 132
__global__ __launch_bounds__(256) void fat_log_bhist_prep(
    const float* eu, const float* ei, int Nu, int Ntot, float* out,
    const int* rows, int nnz, int* bhist,
    const float* tW, const float* tb, u16* Wt1, u16* Bt1,
    const float* dW, const float* db, u16* Wt2, u16* Bt2,
    const float* muW, const float* lvW, u16* WtV,
    const float* f1W, u16* Wt1f, const float* f2W, u16* Wt2f)
{
    __shared__ int h[NB];
    const int b = blockIdx.x;
    if (b < NB_LOG) {
        body_logmap(b, eu, ei, Nu, Ntot, out);
    } else if (b < NB_LOG + NB_HIST) {
        body_bhist(b - NB_LOG, NB_HIST, rows, nnz, bhist, h);
    } else {
        body_prep(b - NB_LOG - NB_HIST, tW, tb, Wt1, Bt1, dW, db, Wt2, Bt2,
                  muW, lvW, WtV, f1W, Wt1f, f2W, Wt2f);
    }
}

#define NB_MOE 1563
__global__ __launch_bounds__(256) void fat_moe_bsc(
    const float* X, float* Y, const u16* Wt, const u16* Bt,
    const float* GW, const float* GB, u16* Bhout, int Ntot,
    const int* rows, const int* cols, const float* vals, int nnz,
    int* gcur, int2* tmp)
{
    __shared__ __align__(16) char smem[21504];
    const int b = blockIdx.x;
    if (b < NB_MOE) {
        body_moe(b, smem, X, Y, Wt, Bt, GW, GB, Bhout, Ntot);
    } else {
        body_bscatter(b - NB_MOE, smem, rows, cols, vals, nnz, gcur, tmp);
    }
}

__global__ __launch_bounds__(256) void fat_vae_sort(
    const float* M, float* Hout, const float* EPSN, const u16* WtV,
    const float* mub, const float* lvb, float* klslot, int Ntot,
    const int2* tmp, const int* bstart, int2* sedge, int* Fout, int nnz)
{
    __shared__ __align__(16) char smem[17664];
    const int b = blockIdx.x;
    if (b < NB_MOE) {
        body_vae(b, smem, M, Hout, EPSN, WtV, mub, lvb, klslot, Ntot);
    } else {
        body_sort(b - NB_MOE, smem, tmp, bstart, sedge, Fout, Ntot, nnz);
    }
}

#define NB_SPMM 25000
__global__ __launch_bounds__(256) void fat_recon_spmm(
    const float* HM, const float* M, int Ntot, float* slot,
    const u16* in, u16* outb, const int* F, const int2* sedge, int nnz)
{
    __shared__ float sb[4];
    const int b = blockIdx.x;
    if (b < NB_LOG) {
        body_recon(b, sb, HM, M, Ntot, slot);
    } else {
        body_spmm(b - NB_LOG, in, outb, F, sedge, Ntot, nnz);
    }
}

// ================= standalone kernels =================

__global__ __launch_bounds__(1024) void k_bscan(const int* __restrict__ bhist,
                                                int* __restrict__ bstart, int* __restrict__ gcur) {
    __shared__ int s[1024];
    const int tid = threadIdx.x;
    int v = (tid < NB) ? bhist[tid] : 0;
    s[tid] = v;
    __syncthreads();
    for (int off = 1; off < 1024; off <<= 1) {
        int t = (tid >= off) ? s[tid - off] : 0;
        __syncthreads();
        s[tid] += t;
        __syncthreads();
    }
    if (tid < NB) {
        bstart[tid + 1] = s[tid];
        gcur[tid] = s[tid] - v;
        if (tid == 0) bstart[0] = 0;
    }
}

__global__ __launch_bounds__(256) void k_moe_mfma(
    const float* __restrict__ X, float* __restrict__ Y,
    const u16* __restrict__ Wt, const u16* __restrict__ Bt,
    const float* __restrict__ GW, const float* __restrict__ GB,
    u16* __restrict__ Bhout, int Ntot)
{
    __shared__ __align__(16) char smem[21504];
    body_moe(blockIdx.x, smem, X, Y, Wt, Bt, GW, GB, Bhout, Ntot);
}

__global__ __launch_bounds__(256) void k_ffn_mfma(
    float* __restrict__ Hio,
    const u16* __restrict__ Wt1f, const float* __restrict__ f1b,
    const u16* __restrict__ Wt2f, const float* __restrict__ f2b, int Ntot)
{
    __shared__ float sH[64][68];
    __shared__ u16 sH1[64][136];
    const int tid = threadIdx.x;
    const int n0 = blockIdx.x * 64;

    for (int i = tid; i < 64 * 16; i += 256) {
        const int rr = i >> 4, cc = i & 15;
        float4 v = make_float4(0.f, 0.f, 0.f, 0.f);
        if (n0 + rr < Ntot) v = *(const float4*)(Hio + (size_t)(n0 + rr) * 64 + cc * 4);
        *(float4*)&sH[rr][cc * 4] = v;
    }
    __syncthreads();

    const int w = tid >> 6, l = tid & 63;
    const int m = l & 15, kq = l >> 4;
    const int rowm = w * 16 + m;

    f32x4 zero = {0.f, 0.f, 0.f, 0.f};
    f32x4 acc1[8];
    #pragma unroll
    for (int t = 0; t < 8; ++t) acc1[t] = zero;

    #pragma unroll
    for (int ks = 0; ks < 2; ++ks) {
        const int k0 = ks * 32 + kq * 8;
        const float4 xa = *(const float4*)&sH[rowm][k0];
        const float4 xb = *(const float4*)&sH[rowm][k0 + 4];
        union { bf16x8 v; u16 u[8]; } af;
        af.u[0] = f2bf(xa.x); af.u[1] = f2bf(xa.y); af.u[2] = f2bf(xa.z); af.u[3] = f2bf(xa.w);
        af.u[4] = f2bf(xb.x); af.u[5] = f2bf(xb.y); af.u[6] = f2bf(xb.z); af.u[7] = f2bf(xb.w);
        #pragma unroll
        for (int t = 0; t < 8; ++t) {
            const bf16x8 bf = *(const bf16x8*)(Wt1f + (((size_t)(t * 16 + m)) << 6) + k0);
            acc1[t] = __builtin_amdgcn_mfma_f32_16x16x32_bf16(af.v, bf, acc1[t], 0, 0, 0);
        }
    }
    #pragma unroll
    for (int t = 0; t < 8; ++t) {
        const float bb = f1b[t * 16 + m];
        #pragma unroll
        for (int r = 0; r < 4; ++r)
            sH1[w * 16 + kq * 4 + r][t * 16 + m] = f2bf(fmaxf(acc1[t][r] + bb, 0.f));
    }
    __syncthreads();

    f32x4 acc2[4];
    #pragma unroll
    for (int t = 0; t < 4; ++t) acc2[t] = zero;
    #pragma unroll
    for (int ks = 0; ks < 4; ++ks) {
        const int k0 = ks * 32 + kq * 8;
        const bf16x8 af = *(const bf16x8*)&sH1[rowm][k0];
        #pragma unroll
        for (int t = 0; t < 4; ++t) {
            const bf16x8 bf = *(const bf16x8*)(Wt2f + (((size_t)(t * 16 + m)) << 7) + k0);
            acc2[t] = __builtin_amdgcn_mfma_f32_16x16x32_bf16(af, bf, acc2[t], 0, 0, 0);
        }
    }
    #pragma unroll
    for (int t = 0; t < 4; ++t) {
        const float bb = f2b[t * 16 + m];
        #pragma unroll
        for (int r = 0; r < 4; ++r) {
            const int row = w * 16 + kq * 4 + r;
            if (n0 + row < Ntot)
                Hio[(size_t)(n0 + row) * 64 + t * 16 + m] = acc2[t][r] + bb;
        }
    }
}

__global__ __launch_bounds__(256) void k_spmm(
    const u16* __restrict__ in, u16* __restrict__ outb,
    const int* __restrict__ F, const int2* __restrict__ sedge, int Ntot, int nnz)
{
    body_spmm(blockIdx.x, in, outb, F, sedge, Ntot, nnz);
}

__global__ __launch_bounds__(256) void k_osum(
    const u16* __restrict__ r1, const u16* __restrict__ r2,
    const u16* __restrict__ r3, u16* __restrict__ outb, int Ntot)
{
    const int lane = threadIdx.x & 63;
    const int g = lane >> 4, q = lane & 15;
    const int n = blockIdx.x * 16 + (threadIdx.x >> 6) * 4 + g;
    if (n >= Ntot) return;
    const size_t ob = ((size_t)n << 6) + q * 4;
    const uint2 a = *(const uint2*)(r1 + ob);
    const uint2 b = *(const uint2*)(r2 + ob);
    const uint2 c = *(const uint2*)(r3 + ob);
    float s0 = bflo(a.x) + bflo(b.x) + bflo(c.x);
    float s1 = bfhi(a.x) + bfhi(b.x) + bfhi(c.x);
    float s2 = bflo(a.y) + bflo(b.y) + bflo(c.y);
    float s3 = bfhi(a.y) + bfhi(b.y) + bfhi(c.y);
    const float v0 = (q == 0) ? 0.f : s0;
    float ss = v0 * v0 + s1 * s1 + s2 * s2 + s3 * s3;
    #pragma unroll
    for (int off = 1; off < 16; off <<= 1) ss += __shfl_xor(ss, off, 64);
    const float nr = fmaxf(sqrtf(ss), EPSF);
    const float r = sinhf(nr) / nr;
    const float sn = r * sqrtf(ss);
    const float scale = fminf(1.0f, MAXNRM / fmaxf(sn, EPSF));
    const float mult = r * scale;
    const float o0 = (q == 0) ? sqrtf(1.0f + mult * mult * ss) : mult * s0;
    uint2 p;
    p.x = (unsigned)f2bf(o0) | ((unsigned)f2bf(mult * s1) << 16);
    p.y = (unsigned)f2bf(mult * s2) | ((unsigned)f2bf(mult * s3) << 16);
    *(uint2*)(outb + ob) = p;
}

__global__ __launch_bounds__(256) void k_triples(
    const u16* __restrict__ Ob, const int* __restrict__ tri,
    int T, float* __restrict__ slot)
{
    const int lane = threadIdx.x & 63;
    const int g = lane >> 4, q = lane & 15;
    const int wid = blockIdx.x * 4 + (threadIdx.x >> 6);
    const int stride = gridDim.x * 4 * 4;

    float racc = 0.f;
    int t = wid * 4 + g;

    uint2 ca, cp, cn;
    if (t < T) {
        const int a = tri[3 * t], p = tri[3 * t + 1], nn = tri[3 * t + 2];
        ca = *(const uint2*)(Ob + (((size_t)a) << 6) + q * 4);
        cp = *(const uint2*)(Ob + (((size_t)p) << 6) + q * 4);
        cn = *(const uint2*)(Ob + (((size_t)nn) << 6) + q * 4);
    }

    for (; t < T; ) {
        const int tn = t + stride;
        const int tc = min(tn, T - 1);
        const int a2 = tri[3 * tc], p2 = tri[3 * tc + 1], n2 = tri[3 * tc + 2];
        const uint2 na_ = *(const uint2*)(Ob + (((size_t)a2) << 6) + q * 4);
        const uint2 np_ = *(const uint2*)(Ob + (((size_t)p2) << 6) + q * 4);
        const uint2 nn_ = *(const uint2*)(Ob + (((size_t)n2) << 6) + q * 4);

        {
            const float a0 = bflo(ca.x), a1 = bfhi(ca.x), a2f = bflo(ca.y), a3 = bfhi(ca.y);
            const float p0 = bflo(cp.x), p1 = bfhi(cp.x), p2f = bflo(cp.y), p3 = bfhi(cp.y);
            const float n0 = bflo(cn.x), n1 = bfhi(cn.x), n2f = bflo(cn.y), n3 = bfhi(cn.y);
            const float s0 = (q == 0) ? -1.f : 1.f;
            float i1 = s0 * a0 * p0 + a1 * p1 + a2f * p2f + a3 * p3;
            float i2 = s0 * a0 * n0 + a1 * n1 + a2f * n2f + a3 * n3;
            #pragma unroll
            for (int off = 1; off < 16; off <<= 1) {
                i1 += __shfl_xor(i1, off, 64);
                i2 += __shfl_xor(i2, off, 64);
            }
            if (q == 0) {
                const float d1 = acoshf(fmaxf(-i1, 1.0f + EPSF));
                const float d2 = acoshf(fmaxf(-i2, 1.0f + EPSF));
                const float l = d1 * d1 - d2 * d2 + 0.1f;
                if (l > 0.f) racc += l;
            }
        }
        ca = na_; cp = np_; cn = nn_;
        t = tn;
    }

    racc = wsum(racc);
    __shared__ float sb[4];
    if (lane == 0) sb[threadIdx.x >> 6] = racc;
    __syncthreads();
    if (threadIdx.x == 0)
        atomicAdd(&slot[blockIdx.x & 255], sb[0] + sb[1] + sb[2] + sb[3]);
}

__global__ void k_final(const float* __restrict__ slots, float* __restrict__ out, int Ntot)
{
    const int tid = threadIdx.x;
    float m = slots[tid], r = slots[256 + tid], k = slots[512 + tid];
    m = wsum(m); r = wsum(r); k = wsum(k);
    __shared__ float sm[4], sr[4], sk[4];
    if ((tid & 63) == 0) { sm[tid >> 6] = m; sr[tid >> 6] = r; sk[tid >> 6] = k; }
    __syncthreads();
    if (tid == 0) {
        const float M = sm[0] + sm[1] + sm[2] + sm[3];
        const float R = sr[0] + sr[1] + sr[2] + sr[3];
        const float K = sk[0] + sk[1] + sk[2] + sk[3];
        const float recon = R / (float)Ntot;
        const float kl = -0.5f * K / ((float)Ntot * 64.0f);
        out[0] = M + 0.1f * (recon + kl);
    }
}

extern "C" void kernel_launch(void* const* d_in, const int* in_sizes, int n_in,
                              void* d_out, int out_size, void* d_ws, size_t ws_size,
                              hipStream_t stream)
{
    const float* emb_user = (const float*)d_in[0];
    const float* emb_item = (const float*)d_in[1];
    const int*   adj_rows = (const int*)d_in[2];
    const int*   adj_cols = (const int*)d_in[3];
    const float* adj_vals = (const float*)d_in[4];
    const int*   triples  = (const int*)d_in[5];
    const float* epsin    = (const float*)d_in[6];
    const float* tW  = (const float*)d_in[7];
    const float* tb  = (const float*)d_in[8];
    const float* tgW = (const float*)d_in[9];
    const float* tgb = (const float*)d_in[10];
    const float* muW = (const float*)d_in[11];
    const float* mub = (const float*)d_in[12];
    const float* lvW = (const float*)d_in[13];
    const float* lvb = (const float*)d_in[14];
    const float* f1W = (const float*)d_in[15];
    const float* f1b = (const float*)d_in[16];
    const float* f2W = (const float*)d_in[17];
    const float* f2b = (const float*)d_in[18];
    const float* dW  = (const float*)d_in[19];
    const float* db  = (const float*)d_in[20];
    const float* dgW = (const float*)d_in[21];
    const float* dgb = (const float*)d_in[22];

    const int Nu = in_sizes[0] / 64, Ni = in_sizes[1] / 64;
    const int N = Nu + Ni;            // 100000
    const int NNZ = in_sizes[4];      // 3200000
    const int T = in_sizes[5] / 3;    // 262144

    float* ws = (float*)d_ws;
    size_t off = 0;
    float* slots = ws + off; off += 1024;            // margin / recon / kl slots
    float* A  = ws + off; off += (size_t)N * 64;     // t -> h; later Hb3 bf16
    float* B  = ws + off; off += (size_t)N * 64;     // m fp32 ; later Ob bf16
    float* C  = ws + off; off += (size_t)N * 64;     // tmp int2; then hm fp32
    float* D  = ws + off; off += (size_t)N * 64;     // sedge (CSR int2[NNZ])
    float* E  = ws + off; off += (size_t)N * 64;     // Bh (-> Hb2) + Hb1 (bf16)
    int*   F  = (int*)(ws + off); off += (size_t)N + 64;   // row starts
    int*   bstart = (int*)(ws + off); off += 1024;
    int*   bhist  = (int*)(ws + off); off += 1024;
    int*   gcur   = (int*)(ws + off); off += 1024;
    u16* Wt1 = (u16*)(ws + off); off += 16384;  // MoE1 8x64x64
    u16* Bt1 = (u16*)(ws + off); off += 256;
    u16* Wt2 = (u16*)(ws + off); off += 16384;  // MoE2
    u16* Bt2 = (u16*)(ws + off); off += 256;
    u16* WtV  = (u16*)(ws + off); off += 4096;  // [mu|lv] 128x64
    u16* Wt1f = (u16*)(ws + off); off += 4096;  // f1W^T 128x64
    u16* Wt2f = (u16*)(ws + off); off += 4096;  // f2W^T 64x128

    int2* tmp   = (int2*)C;                     // C free until moe2 (sort consumes tmp first)
    int2* sedge = (int2*)D;
    u16* Bh  = (u16*)E;                         // dead after spmm1
    u16* Hb1 = (u16*)E + (size_t)N * 64;
    u16* Hb2 = (u16*)E;                         // reuses Bh region (spmm2 output)
    u16* Hb3 = (u16*)A;                         // after moe2 consumed A
    u16* Ob  = (u16*)B;                         // after recon read B

    hipMemsetAsync(slots, 0, 1024 * sizeof(float), stream);
    hipMemsetAsync(bhist, 0, 1024 * sizeof(int), stream);

    const int nb16 = (N + 15) / 16;   // 6250 (== NB_LOG)
    const int nb64 = (N + 63) / 64;   // 1563 (== NB_MOE)
    const int nbN4 = (N + 3) / 4;     // 25000 (== NB_SPMM)
    const int ns1 = (NNZ + 256 * EPT - 1) / (256 * EPT);   // 782 scatter blocks

    // 1. logmap (A) || bhist || all weight prep
    fat_log_bhist_prep<<<NB_LOG + NB_HIST + NB_PREP, 256, 0, stream>>>(
        emb_user, emb_item, Nu, N, A, adj_rows, NNZ, bhist,
        tW, tb, Wt1, Bt1, dW, db, Wt2, Bt2, muW, lvW, WtV, f1W, Wt1f, f2W, Wt2f);

    // 2. bucket scan
    k_bscan<<<1, 1024, 0, stream>>>(bhist, bstart, gcur);

    // 3. moe1 (A->B, Bh) || bscatter (-> tmp=C)
    fat_moe_bsc<<<NB_MOE + ns1, 256, 0, stream>>>(A, B, Wt1, Bt1, tgW, tgb, Bh, N,
                                                  adj_rows, adj_cols, adj_vals, NNZ, gcur, tmp);

    // 4. vae (B->A) || sort (tmp=C -> sedge=D, F)
    fat_vae_sort<<<NB_MOE + NB, 256, 0, stream>>>(B, A, epsin, WtV, mub, lvb, slots + 512, N,
                                                  tmp, bstart, sedge, F, NNZ);

    // 5-6. ffn (A in place), moe2 (A -> C)
    k_ffn_mfma<<<nb64, 256, 0, stream>>>(A, Wt1f, f1b, Wt2f, f2b, N);
    k_moe_mfma<<<nb64, 256, 0, stream>>>(A, C, Wt2, Bt2, dgW, dgb, (u16*)0, N);

    // 7-8. spmm1, spmm2 (standalone, full occupancy)
    k_spmm<<<nbN4, 256, 0, stream>>>(Bh,  Hb1, F, sedge, N, NNZ);
    k_spmm<<<nbN4, 256, 0, stream>>>(Hb1, Hb2, F, sedge, N, NNZ);

    // 9. recon (C,B) || spmm3 (Hb2 -> Hb3 = A) — both lean bodies
    fat_recon_spmm<<<NB_LOG + NB_SPMM, 256, 0, stream>>>(C, B, N, slots + 256,
                                                         Hb2, Hb3, F, sedge, NNZ);

    // 10. out_sum + expmap
    k_osum<<<nb16, 256, 0, stream>>>(Hb1, Hb2, Hb3, Ob, N);

    k_triples<<<2048, 256, 0, stream>>>(Ob, triples, T, slots);
    k_final<<<1, 256, 0, stream>>>(slots, (float*)d_out, N);
}